// Round 2
// baseline (4862.415 us; speedup 1.0000x reference)
//
#include <hip/hip_runtime.h>
#include <math.h>

#define HEADS 4
#define DHEAD 128
#define HD 512     // HEADS*DHEAD
#define NEG 0.2f

// ---------- float <-> monotonic uint mapping for atomicMax on floats ----------
__device__ __forceinline__ unsigned fmap(float f) {
    unsigned u = __float_as_uint(f);
    return u ^ ((u & 0x80000000u) ? 0xFFFFFFFFu : 0x80000000u);
}
__device__ __forceinline__ float funmap(unsigned u) {
    unsigned b = u ^ ((u & 0x80000000u) ? 0x80000000u : 0xFFFFFFFFu);
    return __uint_as_float(b);
}

// ---------- GEMM: out[M,512] = X[M,128] @ W[128,512] + b ----------
// grid.x = row tiles of 64; grid.y in [0,16): tiles 0-7 -> (W_l, xl), 8-15 -> (W_r, xr)
__global__ __launch_bounds__(256) void gemm_xw(
    const float* __restrict__ x,
    const float* __restrict__ Wl, const float* __restrict__ bl,
    const float* __restrict__ Wr, const float* __restrict__ br,
    float* __restrict__ xl, float* __restrict__ xr, int N)
{
    const int colTile = blockIdx.y;
    const float* W; const float* b; float* out; int c0;
    if (colTile < 8) { W = Wl; b = bl; out = xl; c0 = colTile * 64; }
    else             { W = Wr; b = br; out = xr; c0 = (colTile - 8) * 64; }
    const int r0 = blockIdx.x * 64;

    __shared__ float As[64][33];
    __shared__ float Bs[32][65];

    const int tid = threadIdx.x;
    const int ty = tid / 16, tx = tid % 16;
    float acc[4][4] = {};

    for (int k0 = 0; k0 < 128; k0 += 32) {
        // load A tile: 64 rows x 32 cols (8 floats per thread)
        {
            int r = tid >> 2;            // 0..63
            int c = (tid & 3) * 8;       // 0,8,16,24
            int gr = r0 + r;
            float4 v0, v1;
            if (gr < N) {
                const float* p = x + (size_t)gr * 128 + k0 + c;
                v0 = *(const float4*)p;
                v1 = *(const float4*)(p + 4);
            } else {
                v0 = make_float4(0.f, 0.f, 0.f, 0.f); v1 = v0;
            }
            As[r][c + 0] = v0.x; As[r][c + 1] = v0.y; As[r][c + 2] = v0.z; As[r][c + 3] = v0.w;
            As[r][c + 4] = v1.x; As[r][c + 5] = v1.y; As[r][c + 6] = v1.z; As[r][c + 7] = v1.w;
        }
        // load B tile: 32 rows x 64 cols
        {
            int r = tid >> 3;            // 0..31
            int c = (tid & 7) * 8;       // 0..56
            const float* p = W + (size_t)(k0 + r) * 512 + c0 + c;
            float4 v0 = *(const float4*)p;
            float4 v1 = *(const float4*)(p + 4);
            Bs[r][c + 0] = v0.x; Bs[r][c + 1] = v0.y; Bs[r][c + 2] = v0.z; Bs[r][c + 3] = v0.w;
            Bs[r][c + 4] = v1.x; Bs[r][c + 5] = v1.y; Bs[r][c + 6] = v1.z; Bs[r][c + 7] = v1.w;
        }
        __syncthreads();
        #pragma unroll
        for (int kk = 0; kk < 32; ++kk) {
            float a[4], bb[4];
            #pragma unroll
            for (int i = 0; i < 4; ++i) a[i] = As[ty * 4 + i][kk];
            #pragma unroll
            for (int j = 0; j < 4; ++j) bb[j] = Bs[kk][tx * 4 + j];
            #pragma unroll
            for (int i = 0; i < 4; ++i)
                #pragma unroll
                for (int j = 0; j < 4; ++j)
                    acc[i][j] += a[i] * bb[j];
        }
        __syncthreads();
    }
    #pragma unroll
    for (int i = 0; i < 4; ++i) {
        int row = r0 + ty * 4 + i;
        if (row < N) {
            #pragma unroll
            for (int j = 0; j < 4; ++j) {
                int col = c0 + tx * 4 + j;
                out[(size_t)row * 512 + col] = acc[i][j] + b[col];
            }
        }
    }
}

// ---------- per-edge attention score + segment max ----------
// one wave (64 lanes) per edge; lane handles 8 consecutive of the 512 features
__global__ __launch_bounds__(256) void edge_score(
    const int* __restrict__ ei, int E, int N,
    const float* __restrict__ xl, const float* __restrict__ xr,
    const float* __restrict__ att,
    float* __restrict__ ebuf, unsigned* __restrict__ emax)
{
    int wid = (blockIdx.x * 256 + threadIdx.x) >> 6;
    int lane = threadIdx.x & 63;
    int EP = E + N;
    if (wid >= EP) return;
    int src, dst;
    if (wid < E) { src = ei[wid]; dst = ei[E + wid]; }
    else         { src = dst = wid - E; }
    int off = lane * 8;
    int h = lane >> 4;

    const float4* pl = (const float4*)(xl + (size_t)src * HD + off);
    const float4* pr = (const float4*)(xr + (size_t)dst * HD + off);
    const float4* pa = (const float4*)(att + off);
    float4 l0 = pl[0], l1 = pl[1];
    float4 r0 = pr[0], r1 = pr[1];
    float4 a0 = pa[0], a1 = pa[1];

    float s = 0.f, v;
    v = l0.x + r0.x; s += (v > 0.f ? v : NEG * v) * a0.x;
    v = l0.y + r0.y; s += (v > 0.f ? v : NEG * v) * a0.y;
    v = l0.z + r0.z; s += (v > 0.f ? v : NEG * v) * a0.z;
    v = l0.w + r0.w; s += (v > 0.f ? v : NEG * v) * a0.w;
    v = l1.x + r1.x; s += (v > 0.f ? v : NEG * v) * a1.x;
    v = l1.y + r1.y; s += (v > 0.f ? v : NEG * v) * a1.y;
    v = l1.z + r1.z; s += (v > 0.f ? v : NEG * v) * a1.z;
    v = l1.w + r1.w; s += (v > 0.f ? v : NEG * v) * a1.w;

    #pragma unroll
    for (int m = 1; m < 16; m <<= 1) s += __shfl_xor(s, m, 64);

    if ((lane & 15) == 0) {
        ebuf[(size_t)wid * 4 + h] = s;
        atomicMax(&emax[(size_t)dst * 4 + h], fmap(s));
    }
}

// ---------- exp(e - max) and segment sum ----------
__global__ __launch_bounds__(256) void edge_exp(
    const int* __restrict__ ei, int E, int N,
    float* __restrict__ ebuf, const unsigned* __restrict__ emax,
    float* __restrict__ denom)
{
    int id = blockIdx.x * 256 + threadIdx.x;
    int EP = E + N;
    if (id >= EP * 4) return;
    int eid = id >> 2, h = id & 3;
    int dst = (eid < E) ? ei[E + eid] : (eid - E);
    float m = funmap(emax[(size_t)dst * 4 + h]);
    float ee = __expf(ebuf[id] - m);
    ebuf[id] = ee;
    atomicAdd(&denom[(size_t)dst * 4 + h], ee);
}

// ---------- aggregate: out_acc[dst] += alpha * xl[src] ----------
__global__ __launch_bounds__(256) void edge_aggr(
    const int* __restrict__ ei, int E, int N,
    const float* __restrict__ xl, const float* __restrict__ ebuf,
    const float* __restrict__ denom, float* __restrict__ out_acc)
{
    int wid = (blockIdx.x * 256 + threadIdx.x) >> 6;
    int lane = threadIdx.x & 63;
    int EP = E + N;
    if (wid >= EP) return;
    int src, dst;
    if (wid < E) { src = ei[wid]; dst = ei[E + wid]; }
    else         { src = dst = wid - E; }
    int off = lane * 8;
    int h = lane >> 4;

    float ee = ebuf[(size_t)wid * 4 + h];
    float dn = denom[(size_t)dst * 4 + h];
    float alpha = ee / (dn + 1e-16f);

    const float4* pl = (const float4*)(xl + (size_t)src * HD + off);
    float4 l0 = pl[0], l1 = pl[1];
    float* po = out_acc + (size_t)dst * HD + off;
    atomicAdd(po + 0, alpha * l0.x);
    atomicAdd(po + 1, alpha * l0.y);
    atomicAdd(po + 2, alpha * l0.z);
    atomicAdd(po + 3, alpha * l0.w);
    atomicAdd(po + 4, alpha * l1.x);
    atomicAdd(po + 5, alpha * l1.y);
    atomicAdd(po + 6, alpha * l1.z);
    atomicAdd(po + 7, alpha * l1.w);
}

// ---------- head mean + bias -> d_out (pre-BN), BN partial sums ----------
__global__ __launch_bounds__(256) void finalize_a(
    const float* __restrict__ out_acc, const float* __restrict__ bias,
    float* __restrict__ outm, float* __restrict__ musum, float* __restrict__ sqsum,
    int N)
{
    int id = blockIdx.x * 256 + threadIdx.x;
    int n = id >> 7, d = id & 127;
    float v = 0.f;
    if (n < N) {
        const float* p = out_acc + (size_t)n * HD + d;
        v = 0.25f * (p[0] + p[128] + p[256] + p[384]) + bias[d];
        outm[id] = v;
    }
    __shared__ float s1[256], s2[256];
    s1[threadIdx.x] = (n < N) ? v : 0.f;
    s2[threadIdx.x] = (n < N) ? v * v : 0.f;
    __syncthreads();
    if (threadIdx.x < 128) {
        float a = s1[threadIdx.x] + s1[threadIdx.x + 128];
        float c = s2[threadIdx.x] + s2[threadIdx.x + 128];
        atomicAdd(&musum[threadIdx.x], a);
        atomicAdd(&sqsum[threadIdx.x], c);
    }
}

// ---------- BN + ReLU (in place on d_out) ----------
__global__ __launch_bounds__(256) void finalize_b(
    float* __restrict__ outm, const float* __restrict__ musum,
    const float* __restrict__ sqsum, const float* __restrict__ gamma,
    const float* __restrict__ beta, int N)
{
    int id = blockIdx.x * 256 + threadIdx.x;
    if (id >= N * 128) return;
    int d = id & 127;
    float inv_n = 1.0f / (float)N;
    float mu = musum[d] * inv_n;
    float var = sqsum[d] * inv_n - mu * mu;
    float v = gamma[d] * (outm[id] - mu) * rsqrtf(var + 1e-5f) + beta[d];
    outm[id] = v > 0.f ? v : 0.f;
}

extern "C" void kernel_launch(void* const* d_in, const int* in_sizes, int n_in,
                              void* d_out, int out_size, void* d_ws, size_t ws_size,
                              hipStream_t stream) {
    const float* x     = (const float*)d_in[0];
    const int*   ei    = (const int*)d_in[1];      // int inputs arrive as int32
    const float* Wl    = (const float*)d_in[2];
    const float* bl    = (const float*)d_in[3];
    const float* Wr    = (const float*)d_in[4];
    const float* br    = (const float*)d_in[5];
    const float* att   = (const float*)d_in[6];
    const float* bias  = (const float*)d_in[7];
    const float* gamma = (const float*)d_in[8];
    const float* beta  = (const float*)d_in[9];

    const int N = in_sizes[0] / 128;
    const int E = in_sizes[1] / 2;
    const int EP = E + N;

    float* ws      = (float*)d_ws;
    float* xl      = ws;
    float* xr      = xl + (size_t)N * HD;
    float* out_acc = xr + (size_t)N * HD;
    float* ebuf    = out_acc + (size_t)N * HD;
    unsigned* emax = (unsigned*)(ebuf + (size_t)EP * 4);
    float* denom   = (float*)(emax + (size_t)N * 4);
    float* musum   = denom + (size_t)N * 4;
    float* sqsum   = musum + 128;
    float* outm    = (float*)d_out;   // pre-BN values staged in d_out, BN in place

    hipMemsetAsync(out_acc, 0, (size_t)N * HD * sizeof(float), stream);
    hipMemsetAsync(emax, 0, (size_t)N * 4 * sizeof(unsigned), stream);
    hipMemsetAsync(denom, 0, (size_t)N * 4 * sizeof(float), stream);
    hipMemsetAsync(musum, 0, 2 * 128 * sizeof(float), stream);

    dim3 g1((N + 63) / 64, 16);
    gemm_xw<<<g1, 256, 0, stream>>>(x, Wl, bl, Wr, br, xl, xr, N);

    int edge_blocks = (EP + 3) / 4;   // 4 waves per block, 1 wave per edge
    edge_score<<<edge_blocks, 256, 0, stream>>>(ei, E, N, xl, xr, att, ebuf, emax);
    edge_exp<<<(EP * 4 + 255) / 256, 256, 0, stream>>>(ei, E, N, ebuf, emax, denom);
    edge_aggr<<<edge_blocks, 256, 0, stream>>>(ei, E, N, xl, ebuf, denom, out_acc);

    int nd_blocks = (N * 128 + 255) / 256;
    finalize_a<<<nd_blocks, 256, 0, stream>>>(out_acc, bias, outm, musum, sqsum, N);
    finalize_b<<<nd_blocks, 256, 0, stream>>>(outm, musum, sqsum, gamma, beta, N);
}

// Round 3
// 249.809 us; speedup vs baseline: 19.4645x; 19.4645x over previous
//
#include <hip/hip_runtime.h>
#include <math.h>

#define HEADS 4
#define HD 512     // HEADS*DHEAD
#define NEG 0.2f

// ---------- GEMM: out[M,512] = X[M,128] @ W[128,512] + b ----------
__global__ __launch_bounds__(256) void gemm_xw(
    const float* __restrict__ x,
    const float* __restrict__ Wl, const float* __restrict__ bl,
    const float* __restrict__ Wr, const float* __restrict__ br,
    float* __restrict__ xl, float* __restrict__ xr, int N)
{
    const int colTile = blockIdx.y;
    const float* W; const float* b; float* out; int c0;
    if (colTile < 8) { W = Wl; b = bl; out = xl; c0 = colTile * 64; }
    else             { W = Wr; b = br; out = xr; c0 = (colTile - 8) * 64; }
    const int r0 = blockIdx.x * 64;

    __shared__ float As[64][33];
    __shared__ float Bs[32][65];

    const int tid = threadIdx.x;
    const int ty = tid / 16, tx = tid % 16;
    float acc[4][4] = {};

    for (int k0 = 0; k0 < 128; k0 += 32) {
        {
            int r = tid >> 2;
            int c = (tid & 3) * 8;
            int gr = r0 + r;
            float4 v0, v1;
            if (gr < N) {
                const float* p = x + (size_t)gr * 128 + k0 + c;
                v0 = *(const float4*)p;
                v1 = *(const float4*)(p + 4);
            } else {
                v0 = make_float4(0.f, 0.f, 0.f, 0.f); v1 = v0;
            }
            As[r][c + 0] = v0.x; As[r][c + 1] = v0.y; As[r][c + 2] = v0.z; As[r][c + 3] = v0.w;
            As[r][c + 4] = v1.x; As[r][c + 5] = v1.y; As[r][c + 6] = v1.z; As[r][c + 7] = v1.w;
        }
        {
            int r = tid >> 3;
            int c = (tid & 7) * 8;
            const float* p = W + (size_t)(k0 + r) * 512 + c0 + c;
            float4 v0 = *(const float4*)p;
            float4 v1 = *(const float4*)(p + 4);
            Bs[r][c + 0] = v0.x; Bs[r][c + 1] = v0.y; Bs[r][c + 2] = v0.z; Bs[r][c + 3] = v0.w;
            Bs[r][c + 4] = v1.x; Bs[r][c + 5] = v1.y; Bs[r][c + 6] = v1.z; Bs[r][c + 7] = v1.w;
        }
        __syncthreads();
        #pragma unroll
        for (int kk = 0; kk < 32; ++kk) {
            float a[4], bb[4];
            #pragma unroll
            for (int i = 0; i < 4; ++i) a[i] = As[ty * 4 + i][kk];
            #pragma unroll
            for (int j = 0; j < 4; ++j) bb[j] = Bs[kk][tx * 4 + j];
            #pragma unroll
            for (int i = 0; i < 4; ++i)
                #pragma unroll
                for (int j = 0; j < 4; ++j)
                    acc[i][j] += a[i] * bb[j];
        }
        __syncthreads();
    }
    #pragma unroll
    for (int i = 0; i < 4; ++i) {
        int row = r0 + ty * 4 + i;
        if (row < N) {
            #pragma unroll
            for (int j = 0; j < 4; ++j) {
                int col = c0 + tx * 4 + j;
                out[(size_t)row * 512 + col] = acc[i][j] + b[col];
            }
        }
    }
}

// ---------- CSR build ----------
__global__ __launch_bounds__(256) void deg_count(
    const int* __restrict__ ei, int E, int* __restrict__ deg)
{
    int e = blockIdx.x * 256 + threadIdx.x;
    if (e < E) atomicAdd(&deg[ei[E + e]], 1);
}

// single block exclusive scan over deg[0..N) -> rowstart[0..N]
__global__ __launch_bounds__(256) void scan_rowstart(
    const int* __restrict__ deg, int* __restrict__ rowstart, int N)
{
    __shared__ int ssum[256];
    int tid = threadIdx.x;
    int chunk = (N + 255) / 256;
    int start = tid * chunk;
    int end = min(start + chunk, N);
    int s = 0;
    for (int i = start; i < end; ++i) s += deg[i];
    ssum[tid] = s;
    __syncthreads();
    if (tid == 0) {
        int acc = 0;
        for (int i = 0; i < 256; ++i) { int t = ssum[i]; ssum[i] = acc; acc += t; }
    }
    __syncthreads();
    int acc = ssum[tid];
    for (int i = start; i < end; ++i) { rowstart[i] = acc; acc += deg[i]; }
    if (tid == 255) rowstart[N] = acc;
}

__global__ __launch_bounds__(256) void scatter_edges(
    const int* __restrict__ ei, int E, const int* __restrict__ rowstart,
    int* __restrict__ cursor, int* __restrict__ adj)
{
    int e = blockIdx.x * 256 + threadIdx.x;
    if (e >= E) return;
    int src = ei[e], dst = ei[E + e];
    int pos = atomicAdd(&cursor[dst], 1);
    adj[rowstart[dst] + pos] = src;
}

// ---------- fused online-softmax aggregation ----------
// one wave per dst node; lane handles 8 consecutive features; head = lane>>4
__global__ __launch_bounds__(256) void gat_aggr(
    const float* __restrict__ xl, const float* __restrict__ xr,
    const float* __restrict__ att, const float* __restrict__ bias,
    const int* __restrict__ rowstart, const int* __restrict__ adj,
    float* __restrict__ outm, int N)
{
    int wid = (blockIdx.x * 256 + threadIdx.x) >> 6;
    int lane = threadIdx.x & 63;
    if (wid >= N) return;
    const int dst = wid;
    const int off = lane * 8;

    const float4* pr = (const float4*)(xr + (size_t)dst * HD + off);
    float4 r0 = pr[0], r1 = pr[1];
    const float4* pa = (const float4*)(att + off);
    float4 a0 = pa[0], a1 = pa[1];
    float xrv[8] = {r0.x, r0.y, r0.z, r0.w, r1.x, r1.y, r1.z, r1.w};
    float av[8]  = {a0.x, a0.y, a0.z, a0.w, a1.x, a1.y, a1.z, a1.w};

    float m = -3.0e38f, dsum = 0.f;
    float acc[8] = {0.f, 0.f, 0.f, 0.f, 0.f, 0.f, 0.f, 0.f};

    auto process = [&](int src) {
        const float4* pl = (const float4*)(xl + (size_t)src * HD + off);
        float4 l0 = pl[0], l1 = pl[1];
        float xlv[8] = {l0.x, l0.y, l0.z, l0.w, l1.x, l1.y, l1.z, l1.w};
        float s = 0.f;
        #pragma unroll
        for (int j = 0; j < 8; ++j) {
            float v = xlv[j] + xrv[j];
            s += (v > 0.f ? v : NEG * v) * av[j];
        }
        s += __shfl_xor(s, 1, 64);
        s += __shfl_xor(s, 2, 64);
        s += __shfl_xor(s, 4, 64);
        s += __shfl_xor(s, 8, 64);
        float mn  = fmaxf(m, s);
        float scl = __expf(m - mn);   // first iter: exp(-3e38 - s) = 0
        float p   = __expf(s - mn);
        dsum = dsum * scl + p;
        #pragma unroll
        for (int j = 0; j < 8; ++j) acc[j] = acc[j] * scl + p * xlv[j];
        m = mn;
    };

    process(dst);                       // self loop
    int beg = rowstart[dst], end = rowstart[dst + 1];
    int deg = end - beg;
    for (int c0 = 0; c0 < deg; c0 += 64) {
        int myadj = (c0 + lane < deg) ? adj[beg + c0 + lane] : 0;
        int cnt = min(64, deg - c0);
        for (int i = 0; i < cnt; ++i) process(__shfl(myadj, i, 64));
    }

    float inv = 1.f / (dsum + 1e-16f);  // per-head denom (same across 16-lane group)
    #pragma unroll
    for (int j = 0; j < 8; ++j) {
        float v = acc[j] * inv;
        v += __shfl_xor(v, 16, 64);     // sum across 4 heads
        v += __shfl_xor(v, 32, 64);
        if (lane < 16)
            outm[(size_t)dst * 128 + lane * 8 + j] = 0.25f * v + bias[lane * 8 + j];
    }
}

// ---------- BN batch statistics over d_out ----------
__global__ __launch_bounds__(256) void bn_stats(
    const float* __restrict__ outm, float* __restrict__ musum,
    float* __restrict__ sqsum, int N)
{
    int tid = threadIdx.x;
    float s1 = 0.f, s2 = 0.f;
    size_t total = (size_t)N * 128;
    size_t stride = (size_t)gridDim.x * 256;   // multiple of 128 -> d fixed
    for (size_t id = (size_t)blockIdx.x * 256 + tid; id < total; id += stride) {
        float v = outm[id];
        s1 += v; s2 += v * v;
    }
    __shared__ float sh1[256], sh2[256];
    sh1[tid] = s1; sh2[tid] = s2;
    __syncthreads();
    if (tid < 128) {
        atomicAdd(&musum[tid], sh1[tid] + sh1[tid + 128]);
        atomicAdd(&sqsum[tid], sh2[tid] + sh2[tid + 128]);
    }
}

// ---------- BN + ReLU in place on d_out ----------
__global__ __launch_bounds__(256) void finalize_b(
    float* __restrict__ outm, const float* __restrict__ musum,
    const float* __restrict__ sqsum, const float* __restrict__ gamma,
    const float* __restrict__ beta, int N)
{
    int id = blockIdx.x * 256 + threadIdx.x;
    if (id >= N * 128) return;
    int d = id & 127;
    float inv_n = 1.0f / (float)N;
    float mu = musum[d] * inv_n;
    float var = sqsum[d] * inv_n - mu * mu;
    float v = gamma[d] * (outm[id] - mu) * rsqrtf(var + 1e-5f) + beta[d];
    outm[id] = v > 0.f ? v : 0.f;
}

extern "C" void kernel_launch(void* const* d_in, const int* in_sizes, int n_in,
                              void* d_out, int out_size, void* d_ws, size_t ws_size,
                              hipStream_t stream) {
    const float* x     = (const float*)d_in[0];
    const int*   ei    = (const int*)d_in[1];
    const float* Wl    = (const float*)d_in[2];
    const float* bl    = (const float*)d_in[3];
    const float* Wr    = (const float*)d_in[4];
    const float* br    = (const float*)d_in[5];
    const float* att   = (const float*)d_in[6];
    const float* bias  = (const float*)d_in[7];
    const float* gamma = (const float*)d_in[8];
    const float* beta  = (const float*)d_in[9];

    const int N = in_sizes[0] / 128;
    const int E = in_sizes[1] / 2;

    float* ws       = (float*)d_ws;
    float* xl       = ws;
    float* xr       = xl + (size_t)N * HD;
    int*   deg      = (int*)(xr + (size_t)N * HD);
    int*   cursor   = deg + N;
    int*   rowstart = cursor + N;
    int*   adj      = rowstart + (N + 1);
    float* musum    = (float*)(adj + E);
    float* sqsum    = musum + 128;
    float* outm     = (float*)d_out;

    hipMemsetAsync(deg, 0, (size_t)N * sizeof(int), stream);
    hipMemsetAsync(cursor, 0, (size_t)N * sizeof(int), stream);
    hipMemsetAsync(musum, 0, 2 * 128 * sizeof(float), stream);

    dim3 g1((N + 63) / 64, 16);
    gemm_xw<<<g1, 256, 0, stream>>>(x, Wl, bl, Wr, br, xl, xr, N);

    deg_count<<<(E + 255) / 256, 256, 0, stream>>>(ei, E, deg);
    scan_rowstart<<<1, 256, 0, stream>>>(deg, rowstart, N);
    scatter_edges<<<(E + 255) / 256, 256, 0, stream>>>(ei, E, rowstart, cursor, adj);

    gat_aggr<<<(N * 64 + 255) / 256, 256, 0, stream>>>(
        xl, xr, att, bias, rowstart, adj, outm, N);

    bn_stats<<<512, 256, 0, stream>>>(outm, musum, sqsum, N);
    finalize_b<<<(N * 128 + 255) / 256, 256, 0, stream>>>(outm, musum, sqsum, gamma, beta, N);
}

// Round 4
// 200.462 us; speedup vs baseline: 24.2560x; 1.2462x over previous
//
#include <hip/hip_runtime.h>
#include <math.h>

#define HEADS 4
#define HD 512     // HEADS*DHEAD
#define NEG 0.2f

typedef __attribute__((ext_vector_type(8))) short bf16x8;
typedef __attribute__((ext_vector_type(4))) float f32x4;

__device__ __forceinline__ unsigned short f2b(float f) {
    unsigned u = __float_as_uint(f);
    unsigned r = (u + 0x7fff + ((u >> 16) & 1)) >> 16;   // RNE
    return (unsigned short)r;
}
__device__ __forceinline__ float lo16(unsigned u) { return __uint_as_float(u << 16); }
__device__ __forceinline__ float hi16(unsigned u) { return __uint_as_float(u & 0xffff0000u); }

// ---------- convert x -> bf16 ----------
__global__ __launch_bounds__(256) void cvt_x(
    const float* __restrict__ x, unsigned short* __restrict__ xb, int n4)
{
    int i = blockIdx.x * 256 + threadIdx.x;
    if (i >= n4) return;
    float4 v = ((const float4*)x)[i];
    ushort4 o;
    o.x = f2b(v.x); o.y = f2b(v.y); o.z = f2b(v.z); o.w = f2b(v.w);
    ((ushort4*)xb)[i] = o;
}

// ---------- convert + transpose W[128,512] -> Wt[512,128] bf16 (both weights) ----------
__global__ __launch_bounds__(256) void cvt_w(
    const float* __restrict__ Wl, const float* __restrict__ Wr,
    unsigned short* __restrict__ wlt, unsigned short* __restrict__ wrt)
{
    int id = blockIdx.x * 256 + threadIdx.x;
    if (id >= 2 * 65536) return;
    const float* W = (id < 65536) ? Wl : Wr;
    unsigned short* Wt = (id < 65536) ? wlt : wrt;
    int e = id & 65535;
    int c = e >> 7, k = e & 127;
    Wt[c * 128 + k] = f2b(W[k * 512 + c]);
}

// ---------- MFMA GEMM: out[M,512] = x[M,128] @ W + b ----------
// grid.y in [0,8): y>>2 selects weight (0 -> xl bf16 out, 1 -> xr f32 out),
// (y&3)*128 is the column block. Block = 4 waves, each wave: 16 rows x 128 cols.
__global__ __launch_bounds__(256) void gemm_mfma(
    const unsigned short* __restrict__ xb,
    const unsigned short* __restrict__ wlt, const unsigned short* __restrict__ wrt,
    const float* __restrict__ bl, const float* __restrict__ br,
    unsigned short* __restrict__ xlb, float* __restrict__ xr, int N)
{
    const int wv = threadIdx.x >> 6;
    const int lane = threadIdx.x & 63;
    const int wsel = blockIdx.y >> 2;
    const int cb0 = (blockIdx.y & 3) * 128;
    const unsigned short* Wt = wsel ? wrt : wlt;
    const float* bias = wsel ? br : bl;

    const int r0 = blockIdx.x * 64 + wv * 16;
    const int row16 = lane & 15;
    const int kg = lane >> 4;          // k-group 0..3, 8 contiguous k each
    int ar = r0 + row16;
    int arc = (ar < N) ? ar : (N - 1);

    f32x4 acc[8];
    #pragma unroll
    for (int i = 0; i < 8; ++i) acc[i] = (f32x4){0.f, 0.f, 0.f, 0.f};

    #pragma unroll
    for (int ks = 0; ks < 4; ++ks) {
        bf16x8 a = *(const bf16x8*)(xb + (size_t)arc * 128 + ks * 32 + kg * 8);
        #pragma unroll
        for (int cb = 0; cb < 8; ++cb) {
            int col = cb0 + cb * 16 + row16;
            bf16x8 b = *(const bf16x8*)(Wt + (size_t)col * 128 + ks * 32 + kg * 8);
            acc[cb] = __builtin_amdgcn_mfma_f32_16x16x32_bf16(a, b, acc[cb], 0, 0, 0);
        }
    }

    // C/D layout: col = lane&15, row = (lane>>4)*4 + reg  [HW-verified]
    #pragma unroll
    for (int cb = 0; cb < 8; ++cb) {
        int col = cb0 + cb * 16 + row16;
        float bv = bias[col];
        #pragma unroll
        for (int r = 0; r < 4; ++r) {
            int row = r0 + kg * 4 + r;
            if (row < N) {
                float v = acc[cb][r] + bv;
                if (wsel == 0) xlb[(size_t)row * 512 + col] = f2b(v);
                else           xr[(size_t)row * 512 + col] = v;
            }
        }
    }
}

// ---------- CSR build ----------
__global__ __launch_bounds__(256) void deg_count(
    const int* __restrict__ ei, int E, int* __restrict__ deg)
{
    int e = blockIdx.x * 256 + threadIdx.x;
    if (e < E) atomicAdd(&deg[ei[E + e]], 1);
}

__global__ __launch_bounds__(256) void scan_rowstart(
    const int* __restrict__ deg, int* __restrict__ rowstart, int N)
{
    __shared__ int ssum[256];
    int tid = threadIdx.x;
    int chunk = (N + 255) / 256;
    int start = tid * chunk;
    int end = min(start + chunk, N);
    int s = 0;
    for (int i = start; i < end; ++i) s += deg[i];
    ssum[tid] = s;
    __syncthreads();
    if (tid == 0) {
        int acc = 0;
        for (int i = 0; i < 256; ++i) { int t = ssum[i]; ssum[i] = acc; acc += t; }
    }
    __syncthreads();
    int acc = ssum[tid];
    for (int i = start; i < end; ++i) { rowstart[i] = acc; acc += deg[i]; }
    if (tid == 255) rowstart[N] = acc;
}

__global__ __launch_bounds__(256) void scatter_edges(
    const int* __restrict__ ei, int E, const int* __restrict__ rowstart,
    int* __restrict__ cursor, int* __restrict__ adj)
{
    int e = blockIdx.x * 256 + threadIdx.x;
    if (e >= E) return;
    int src = ei[e], dst = ei[E + e];
    int pos = atomicAdd(&cursor[dst], 1);
    adj[rowstart[dst] + pos] = src;
}

// ---------- fused online-softmax aggregation (bf16 xl gather) ----------
// one wave per dst node; lane handles 8 consecutive features; head = lane>>4
__global__ __launch_bounds__(256) void gat_aggr(
    const unsigned short* __restrict__ xlb, const float* __restrict__ xr,
    const float* __restrict__ att, const float* __restrict__ bias,
    const int* __restrict__ rowstart, const int* __restrict__ adj,
    float* __restrict__ outm, int N)
{
    int wid = (blockIdx.x * 256 + threadIdx.x) >> 6;
    int lane = threadIdx.x & 63;
    if (wid >= N) return;
    const int dst = wid;
    const int off = lane * 8;

    const float4* pr = (const float4*)(xr + (size_t)dst * HD + off);
    float4 r0 = pr[0], r1 = pr[1];
    const float4* pa = (const float4*)(att + off);
    float4 a0 = pa[0], a1 = pa[1];
    float xrv[8] = {r0.x, r0.y, r0.z, r0.w, r1.x, r1.y, r1.z, r1.w};
    float av[8]  = {a0.x, a0.y, a0.z, a0.w, a1.x, a1.y, a1.z, a1.w};

    float m = -3.0e38f, dsum = 0.f;
    float acc[8] = {0.f, 0.f, 0.f, 0.f, 0.f, 0.f, 0.f, 0.f};

    auto process = [&](int src) {
        uint4 u = *(const uint4*)(xlb + (size_t)src * HD + off);
        float xlv[8] = {lo16(u.x), hi16(u.x), lo16(u.y), hi16(u.y),
                        lo16(u.z), hi16(u.z), lo16(u.w), hi16(u.w)};
        float s = 0.f;
        #pragma unroll
        for (int j = 0; j < 8; ++j) {
            float v = xlv[j] + xrv[j];
            s += (v > 0.f ? v : NEG * v) * av[j];
        }
        s += __shfl_xor(s, 1, 64);
        s += __shfl_xor(s, 2, 64);
        s += __shfl_xor(s, 4, 64);
        s += __shfl_xor(s, 8, 64);
        float mn  = fmaxf(m, s);
        float scl = __expf(m - mn);
        float p   = __expf(s - mn);
        dsum = dsum * scl + p;
        #pragma unroll
        for (int j = 0; j < 8; ++j) acc[j] = acc[j] * scl + p * xlv[j];
        m = mn;
    };

    process(dst);                       // self loop
    int beg = rowstart[dst], end = rowstart[dst + 1];
    int deg = end - beg;
    for (int c0 = 0; c0 < deg; c0 += 64) {
        int myadj = (c0 + lane < deg) ? adj[beg + c0 + lane] : 0;
        int cnt = min(64, deg - c0);
        for (int i = 0; i < cnt; ++i) process(__shfl(myadj, i, 64));
    }

    float inv = 1.f / (dsum + 1e-16f);
    #pragma unroll
    for (int j = 0; j < 8; ++j) {
        float v = acc[j] * inv;
        v += __shfl_xor(v, 16, 64);     // sum across 4 heads
        v += __shfl_xor(v, 32, 64);
        if (lane < 16)
            outm[(size_t)dst * 128 + lane * 8 + j] = 0.25f * v + bias[lane * 8 + j];
    }
}

// ---------- BN batch statistics ----------
__global__ __launch_bounds__(256) void bn_stats(
    const float* __restrict__ outm, float* __restrict__ musum,
    float* __restrict__ sqsum, int N)
{
    int tid = threadIdx.x;
    float s1 = 0.f, s2 = 0.f;
    size_t total = (size_t)N * 128;
    size_t stride = (size_t)gridDim.x * 256;
    for (size_t id = (size_t)blockIdx.x * 256 + tid; id < total; id += stride) {
        float v = outm[id];
        s1 += v; s2 += v * v;
    }
    __shared__ float sh1[256], sh2[256];
    sh1[tid] = s1; sh2[tid] = s2;
    __syncthreads();
    if (tid < 128) {
        atomicAdd(&musum[tid], sh1[tid] + sh1[tid + 128]);
        atomicAdd(&sqsum[tid], sh2[tid] + sh2[tid + 128]);
    }
}

// ---------- BN + ReLU in place on d_out ----------
__global__ __launch_bounds__(256) void finalize_b(
    float* __restrict__ outm, const float* __restrict__ musum,
    const float* __restrict__ sqsum, const float* __restrict__ gamma,
    const float* __restrict__ beta, int N)
{
    int id = blockIdx.x * 256 + threadIdx.x;
    if (id >= N * 128) return;
    int d = id & 127;
    float inv_n = 1.0f / (float)N;
    float mu = musum[d] * inv_n;
    float var = sqsum[d] * inv_n - mu * mu;
    float v = gamma[d] * (outm[id] - mu) * rsqrtf(var + 1e-5f) + beta[d];
    outm[id] = v > 0.f ? v : 0.f;
}

extern "C" void kernel_launch(void* const* d_in, const int* in_sizes, int n_in,
                              void* d_out, int out_size, void* d_ws, size_t ws_size,
                              hipStream_t stream) {
    const float* x     = (const float*)d_in[0];
    const int*   ei    = (const int*)d_in[1];
    const float* Wl    = (const float*)d_in[2];
    const float* bl    = (const float*)d_in[3];
    const float* Wr    = (const float*)d_in[4];
    const float* br    = (const float*)d_in[5];
    const float* att   = (const float*)d_in[6];
    const float* bias  = (const float*)d_in[7];
    const float* gamma = (const float*)d_in[8];
    const float* beta  = (const float*)d_in[9];

    const int N = in_sizes[0] / 128;
    const int E = in_sizes[1] / 2;

    float*          xr  = (float*)d_ws;                        // N*512 f32
    unsigned short* xlb = (unsigned short*)(xr + (size_t)N * 512);  // N*512 bf16
    unsigned short* xb  = xlb + (size_t)N * 512;               // N*128 bf16
    unsigned short* wlt = xb + (size_t)N * 128;                // 512*128 bf16
    unsigned short* wrt = wlt + 65536;
    int* deg      = (int*)(wrt + 65536);
    int* cursor   = deg + N;
    int* rowstart = cursor + N;
    int* adj      = rowstart + (N + 1);
    float* musum  = (float*)(adj + E);
    float* sqsum  = musum + 128;
    float* outm   = (float*)d_out;

    hipMemsetAsync(deg, 0, (size_t)N * sizeof(int), stream);
    hipMemsetAsync(cursor, 0, (size_t)N * sizeof(int), stream);
    hipMemsetAsync(musum, 0, 2 * 128 * sizeof(float), stream);

    int n4 = N * 128 / 4;
    cvt_x<<<(n4 + 255) / 256, 256, 0, stream>>>(x, xb, n4);
    cvt_w<<<(2 * 65536 + 255) / 256, 256, 0, stream>>>(Wl, Wr, wlt, wrt);

    dim3 gg((N + 63) / 64, 8);
    gemm_mfma<<<gg, 256, 0, stream>>>(xb, wlt, wrt, bl, br, xlb, xr, N);

    deg_count<<<(E + 255) / 256, 256, 0, stream>>>(ei, E, deg);
    scan_rowstart<<<1, 256, 0, stream>>>(deg, rowstart, N);
    scatter_edges<<<(E + 255) / 256, 256, 0, stream>>>(ei, E, rowstart, cursor, adj);

    gat_aggr<<<(N * 64 + 255) / 256, 256, 0, stream>>>(
        xlb, xr, att, bias, rowstart, adj, outm, N);

    bn_stats<<<512, 256, 0, stream>>>(outm, musum, sqsum, N);
    finalize_b<<<(N * 128 + 255) / 256, 256, 0, stream>>>(outm, musum, sqsum, gamma, beta, N);
}